// Round 7
// baseline (372.624 us; speedup 1.0000x reference)
//
#include <hip/hip_runtime.h>
#include <hip/hip_bf16.h>
#include <math.h>

#define HID 576
#define NHEADS 9
#define KVHEADS 3
#define HD 64
#define SEQ 4096
#define NBATCH 2

typedef __attribute__((ext_vector_type(8))) short short8;
typedef __attribute__((ext_vector_type(4))) float f32x4;
typedef __attribute__((ext_vector_type(16))) float f32x16;
typedef __attribute__((ext_vector_type(4))) unsigned int u32x4;

#define EXP2F(x) exp2f(x)

// 0.125 (1/sqrt(64)) * log2(e): folded into Q so softmax runs in exp2 domain
#define QSCALE 0.18033688011112042f

#define NBH (NBATCH*NHEADS)            // 18
#define NQ32 (SEQ/32)                  // 128 32-row q-blocks per (b,h)

__device__ __forceinline__ unsigned short f2bf(float f){
  unsigned int u = __float_as_uint(f);
  u += 0x7FFFu + ((u >> 16) & 1u);
  return (unsigned short)(u >> 16);
}
__device__ __forceinline__ float bf2f(unsigned short u){
  return __uint_as_float(((unsigned)u) << 16);
}

__device__ __forceinline__ unsigned cvt_pk_bf16(float lo, float hi){
  unsigned r;
  asm("v_cvt_pk_bf16_f32 %0, %1, %2" : "=v"(r) : "v"(lo), "v"(hi));
  return r;
}

// ---------------- cast x (fp32) -> bf16 ----------------
__global__ __launch_bounds__(256) void k_cast(const float* __restrict__ x,
                                              unsigned short* __restrict__ xb, int n){
  int i = (blockIdx.x * 256 + threadIdx.x) * 4;
  if (i < n){
    float4 v = *(const float4*)(x + i);
    ushort4 o;
    o.x = f2bf(v.x); o.y = f2bf(v.y); o.z = f2bf(v.z); o.w = f2bf(v.w);
    *(ushort4*)(xb + i) = o;
  }
}

// ---------------- fused QKV GEMM + RoPE (Q pre-scaled by 0.125*log2e) ----------------
__global__ __launch_bounds__(256) void k_qkv(const unsigned short* __restrict__ xb,
    const float* __restrict__ Wq, const float* __restrict__ Wk, const float* __restrict__ Wv,
    unsigned short* __restrict__ Qo, unsigned short* __restrict__ Ko,
    unsigned short* __restrict__ Vt)
{
  __shared__ unsigned short As[64][40];
  __shared__ unsigned short Bs[64][40];
  const int tn = blockIdx.x;
  const int m0 = blockIdx.y * 64;
  const int t  = threadIdx.x;
  const int w  = t >> 6;
  const int l  = t & 63;
  const int l15 = l & 15, lg = l >> 4;

  const float* W; int nb, ldw;
  if (tn < 9)      { W = Wq; nb = tn * 64;        ldw = 576; }
  else if (tn < 12){ W = Wk; nb = (tn - 9) * 64;  ldw = 192; }
  else             { W = Wv; nb = (tn - 12) * 64; ldw = 192; }

  f32x4 acc[4];
  #pragma unroll
  for (int n = 0; n < 4; ++n){ f32x4 z = {0.f,0.f,0.f,0.f}; acc[n] = z; }

  const int ar = t >> 2, ac = (t & 3) * 8;
  const int bkr = t >> 3, bnc = (t & 7) * 8;

  for (int kt = 0; kt < 18; ++kt){
    const int k0 = kt * 32;
    *(short8*)&As[ar][ac] = *(const short8*)(xb + (m0 + ar) * 576 + k0 + ac);
    {
      const float* src = W + (k0 + bkr) * ldw + nb + bnc;
      float4 v0 = *(const float4*)src;
      float4 v1 = *(const float4*)(src + 4);
      Bs[bnc+0][bkr] = f2bf(v0.x); Bs[bnc+1][bkr] = f2bf(v0.y);
      Bs[bnc+2][bkr] = f2bf(v0.z); Bs[bnc+3][bkr] = f2bf(v0.w);
      Bs[bnc+4][bkr] = f2bf(v1.x); Bs[bnc+5][bkr] = f2bf(v1.y);
      Bs[bnc+6][bkr] = f2bf(v1.z); Bs[bnc+7][bkr] = f2bf(v1.w);
    }
    __syncthreads();
    short8 af = *(const short8*)&As[w*16 + l15][lg*8];
    #pragma unroll
    for (int n = 0; n < 4; ++n){
      short8 bf = *(const short8*)&Bs[n*16 + l15][lg*8];
      acc[n] = __builtin_amdgcn_mfma_f32_16x16x32_bf16(af, bf, acc[n], 0, 0, 0);
    }
    __syncthreads();
  }

  // RoPE: pairs (d, d+32) = frags (n, n+2), same lane, same reg.
  if (tn < 12){
    #pragma unroll
    for (int np = 0; np < 2; ++np){
      const int p = np*16 + l15;
      const float freq = exp2f((float)p * -0.41524101186f);  // 10000^(-p/32)
      #pragma unroll
      for (int reg = 0; reg < 4; ++reg){
        const int grow = m0 + w*16 + lg*4 + reg;
        const int s = grow & (SEQ-1);
        float si, co;
        sincosf((float)s * freq, &si, &co);
        float v0 = acc[np][reg], v1 = acc[np+2][reg];
        acc[np][reg]   = v0*co - v1*si;
        acc[np+2][reg] = v1*co + v0*si;
      }
    }
  }

  if (tn < 9){
    const int h = tn;
    #pragma unroll
    for (int reg = 0; reg < 4; ++reg){
      const int grow = m0 + w*16 + lg*4 + reg;
      const int b = grow >> 12, s = grow & (SEQ-1);
      unsigned short* dst = Qo + ((b*NHEADS + h)*SEQ + s)*64;
      #pragma unroll
      for (int n = 0; n < 4; ++n) dst[n*16 + l15] = f2bf(acc[n][reg] * QSCALE);
    }
  } else if (tn < 12){
    const int h = tn - 9;
    #pragma unroll
    for (int reg = 0; reg < 4; ++reg){
      const int grow = m0 + w*16 + lg*4 + reg;
      const int b = grow >> 12, s = grow & (SEQ-1);
      unsigned short* dst = Ko + ((b*KVHEADS + h)*SEQ + s)*64;
      #pragma unroll
      for (int n = 0; n < 4; ++n) dst[n*16 + l15] = f2bf(acc[n][reg]);
    }
  } else {
    const int h = tn - 12;
    #pragma unroll
    for (int reg = 0; reg < 4; ++reg){
      const int grow = m0 + w*16 + lg*4 + reg;
      const int b = grow >> 12, s = grow & (SEQ-1);
      #pragma unroll
      for (int n = 0; n < 4; ++n)
        Vt[((b*KVHEADS + h)*64 + n*16 + l15)*SEQ + s] = f2bf(acc[n][reg]);
    }
  }
}

// ---------------- causal flash attention, chunked split-K ----------------
// Every item (qb, bh) is cut into nch = ceil((qb+1)/CS) chunks of CS subtiles.
// Tier t = qb/CS (items in tier t have nch = t+1). Tier T-1 dispatched first.
// Tier-0 chunks write AO directly; others write bf16 partials merged by k_comb.
__global__ __launch_bounds__(64, 4) void k_attn6(const unsigned short* __restrict__ Q,
    const unsigned short* __restrict__ K, const unsigned short* __restrict__ Vt,
    unsigned short* __restrict__ AO,
    unsigned short* __restrict__ PO, float* __restrict__ Pm, float* __restrict__ Pl,
    int CS, int T)
{
  const int w_id = blockIdx.x;
  int off = 0, tt = 0, wrel = 0;
  for (int t = T - 1; t >= 0; --t){
    const int nt = NBH * CS * (t + 1);
    if (w_id < off + nt){ tt = t; wrel = w_id - off; break; }
    off += nt;
  }
  const int i   = wrel / (tt + 1);
  const int c   = wrel % (tt + 1);
  const int qb  = CS*tt + CS-1 - i / NBH;
  const int bh  = i % NBH;
  const int s0  = c * CS;
  const int s1  = min(s0 + CS, qb + 1);
  const bool partial = (tt > 0);

  const int b  = bh / NHEADS, h = bh % NHEADS, kvh = h / 3;
  const int l  = threadIdx.x;
  const int q31 = l & 31, half = l >> 5;
  const int q0 = qb * 32;
  const int myq = q0 + q31;

  const unsigned short* Qp = Q + ((size_t)(b*NHEADS + h)*SEQ + q0 + q31)*HD + half*8;
  const short8 qf0 = *(const short8*)(Qp);
  const short8 qf1 = *(const short8*)(Qp + 16);
  const short8 qf2 = *(const short8*)(Qp + 32);
  const short8 qf3 = *(const short8*)(Qp + 48);

  const unsigned short* Kp  = K  + (size_t)(b*KVHEADS + kvh)*SEQ*HD + (size_t)q31*HD + half*8;
  const unsigned short* Vp0 = Vt + (size_t)(b*KVHEADS + kvh)*HD*SEQ + (size_t)q31*SEQ + half*8;
  const unsigned short* Vp1 = Vp0 + (size_t)32*SEQ;

  f32x16 acc0 = {};  // O rows=q, lane col q31 = d (0..31)
  f32x16 acc1 = {};  // d 32..63
  float m_run = -3e38f, lsum = 0.f;

  // prefetch K fragments for first subtile
  const unsigned short* kp0 = Kp + (size_t)(s0*32)*HD;
  short8 ckf0 = *(const short8*)(kp0);
  short8 ckf1 = *(const short8*)(kp0 + 16);
  short8 ckf2 = *(const short8*)(kp0 + 32);
  short8 ckf3 = *(const short8*)(kp0 + 48);

  for (int s = s0; s < s1; ++s){
    const int ks = s*32;

    // V loads for current subtile (consumed at the end -> latency hidden)
    short8 vf00 = *(const short8*)(Vp0 + ks);
    short8 vf01 = *(const short8*)(Vp0 + ks + 16);
    short8 vf10 = *(const short8*)(Vp1 + ks);
    short8 vf11 = *(const short8*)(Vp1 + ks + 16);

    // ---- QK^T (swapped): ST[k][q], col=q31 -> q, row k = (r&3)+8*(r>>2)+4*half
    __builtin_amdgcn_s_setprio(1);
    f32x16 st = {};
    st = __builtin_amdgcn_mfma_f32_32x32x16_bf16(ckf0, qf0, st, 0,0,0);
    st = __builtin_amdgcn_mfma_f32_32x32x16_bf16(ckf1, qf1, st, 0,0,0);
    st = __builtin_amdgcn_mfma_f32_32x32x16_bf16(ckf2, qf2, st, 0,0,0);
    st = __builtin_amdgcn_mfma_f32_32x32x16_bf16(ckf3, qf3, st, 0,0,0);
    __builtin_amdgcn_s_setprio(0);

    // prefetch next subtile's K fragments (hidden under softmax+pack+PV)
    short8 nkf0, nkf1, nkf2, nkf3;
    const bool more = (s + 1 < s1);
    if (more){
      const unsigned short* kp = Kp + (size_t)(ks + 32)*HD;
      nkf0 = *(const short8*)(kp);
      nkf1 = *(const short8*)(kp + 16);
      nkf2 = *(const short8*)(kp + 32);
      nkf3 = *(const short8*)(kp + 48);
    }

    // causal mask: only the diagonal subtile needs it
    if (s == qb){
      #pragma unroll
      for (int r = 0; r < 16; ++r){
        const int k = ks + (r & 3) + 8*(r >> 2) + 4*half;
        if (k > myq) st[r] = -3e38f;
      }
    }

    // row max: depth-4 tree + cross-half
    float a0 = fmaxf(st[0], st[1]),  a1 = fmaxf(st[2], st[3]);
    float a2 = fmaxf(st[4], st[5]),  a3 = fmaxf(st[6], st[7]);
    float a4 = fmaxf(st[8], st[9]),  a5 = fmaxf(st[10], st[11]);
    float a6 = fmaxf(st[12], st[13]),a7 = fmaxf(st[14], st[15]);
    float b0 = fmaxf(a0, a1), b1 = fmaxf(a2, a3), b2 = fmaxf(a4, a5), b3 = fmaxf(a6, a7);
    float pmax = fmaxf(fmaxf(b0, b1), fmaxf(b2, b3));
    pmax = fmaxf(pmax, __shfl_xor(pmax, 32));

    // deferred rescale (T13)
    if (__any(pmax > m_run + 8.0f)){
      const float mnew  = fmaxf(m_run, pmax);
      const float alpha = EXP2F(m_run - mnew);
      m_run = mnew;
      lsum *= alpha;
      #pragma unroll
      for (int r = 0; r < 16; ++r){
        const float ar = __shfl(alpha, (r & 3) + 8*(r >> 2) + 4*half);
        acc0[r] *= ar; acc1[r] *= ar;
      }
    }

    // P = exp2(st - m); row sum
    float psum = 0.f;
    #pragma unroll
    for (int r = 0; r < 16; ++r){ st[r] = EXP2F(st[r] - m_run); psum += st[r]; }
    psum += __shfl_xor(psum, 32);
    lsum += psum;

    // pack P -> PV A-frags via v_permlane32_swap (T12)
    union { u32x4 u; short8 s; } pa0, pa1;
    {
      unsigned cA = cvt_pk_bf16(st[0], st[1]);
      unsigned cB = cvt_pk_bf16(st[2], st[3]);
      unsigned cC = cvt_pk_bf16(st[4], st[5]);
      unsigned cD = cvt_pk_bf16(st[6], st[7]);
      asm("v_permlane32_swap_b32 %0, %1" : "+v"(cA), "+v"(cC));
      asm("v_permlane32_swap_b32 %0, %1" : "+v"(cB), "+v"(cD));
      pa0.u[0] = cA; pa0.u[1] = cB; pa0.u[2] = cC; pa0.u[3] = cD;
      unsigned eA = cvt_pk_bf16(st[8],  st[9]);
      unsigned eB = cvt_pk_bf16(st[10], st[11]);
      unsigned eC = cvt_pk_bf16(st[12], st[13]);
      unsigned eD = cvt_pk_bf16(st[14], st[15]);
      asm("v_permlane32_swap_b32 %0, %1" : "+v"(eA), "+v"(eC));
      asm("v_permlane32_swap_b32 %0, %1" : "+v"(eB), "+v"(eD));
      pa1.u[0] = eA; pa1.u[1] = eB; pa1.u[2] = eC; pa1.u[3] = eD;
    }

    // PV: O += P · V
    __builtin_amdgcn_s_setprio(1);
    acc0 = __builtin_amdgcn_mfma_f32_32x32x16_bf16(pa0.s, vf00, acc0, 0,0,0);
    acc0 = __builtin_amdgcn_mfma_f32_32x32x16_bf16(pa1.s, vf01, acc0, 0,0,0);
    acc1 = __builtin_amdgcn_mfma_f32_32x32x16_bf16(pa0.s, vf10, acc1, 0,0,0);
    acc1 = __builtin_amdgcn_mfma_f32_32x32x16_bf16(pa1.s, vf11, acc1, 0,0,0);
    __builtin_amdgcn_s_setprio(0);

    if (more){ ckf0 = nkf0; ckf1 = nkf1; ckf2 = nkf2; ckf3 = nkf3; }
  }

  if (partial){
    unsigned short* POp = PO + (size_t)w_id * (32*64);
    #pragma unroll
    for (int r = 0; r < 16; ++r){
      const int rq = (r & 3) + 8*(r >> 2) + 4*half;
      POp[rq*64 + q31]      = f2bf(acc0[r]);
      POp[rq*64 + q31 + 32] = f2bf(acc1[r]);
    }
    if (half == 0){
      Pm[(size_t)w_id*32 + q31] = m_run;
      Pl[(size_t)w_id*32 + q31] = lsum;
    }
  } else {
    const float linv = 1.0f / lsum;
    #pragma unroll
    for (int r = 0; r < 16; ++r){
      const int rq = (r & 3) + 8*(r >> 2) + 4*half;
      const float lr = __shfl(linv, rq);
      const size_t base = ((size_t)(b*SEQ + q0 + rq))*576 + h*64 + q31;
      AO[base]      = f2bf(acc0[r] * lr);
      AO[base + 32] = f2bf(acc1[r] * lr);
    }
  }
}

// ---------------- merge chunked split-K partials (array-free: two passes) ----------------
__global__ __launch_bounds__(64) void k_comb(const unsigned short* __restrict__ PO,
    const float* __restrict__ Pm, const float* __restrict__ Pl,
    unsigned short* __restrict__ AO, int CS, int T)
{
  const int m  = blockIdx.x;               // items with qb >= CS
  const int qb = (NQ32 - 1) - m / NBH;
  const int bh = m % NBH;
  const int b = bh / NHEADS, h = bh % NHEADS;
  const int q0 = qb * 32;
  const int d = threadIdx.x;               // 0..63

  const int t = qb / CS;
  int base = 0;
  for (int t2 = T - 1; t2 > t; --t2) base += NBH * CS * (t2 + 1);
  const int i = (CS*t + CS-1 - qb) * NBH + bh;
  const int slot0 = base + i * (t + 1);
  const int nch = t + 1;

  for (int row = 0; row < 32; ++row){
    // pass 1: global max over chunks
    float M = -3e38f;
    for (int c = 0; c < nch; ++c)
      M = fmaxf(M, Pm[(size_t)(slot0 + c)*32 + row]);
    // pass 2: weighted accumulate (Pm/Pl re-read from L2)
    float lsum = 0.f, o = 0.f;
    for (int c = 0; c < nch; ++c){
      const float wc = exp2f(Pm[(size_t)(slot0 + c)*32 + row] - M);
      lsum += Pl[(size_t)(slot0 + c)*32 + row] * wc;
      o += bf2f(PO[(size_t)(slot0 + c)*(32*64) + row*64 + d]) * wc;
    }
    AO[((size_t)(b*SEQ + q0 + row))*576 + h*64 + d] = f2bf(o / lsum);
  }
}

// ---------------- output projection: AO(bf16) @ Wo -> out(fp32) ----------------
__global__ __launch_bounds__(256) void k_oproj(const unsigned short* __restrict__ AO,
    const float* __restrict__ Wo, float* __restrict__ out)
{
  __shared__ unsigned short As[64][40];
  __shared__ unsigned short Bs[64][40];
  const int tn = blockIdx.x;
  const int m0 = blockIdx.y * 64;
  const int t  = threadIdx.x;
  const int w  = t >> 6;
  const int l  = t & 63;
  const int l15 = l & 15, lg = l >> 4;
  const int nb = tn * 64;

  f32x4 acc[4];
  #pragma unroll
  for (int n = 0; n < 4; ++n){ f32x4 z = {0.f,0.f,0.f,0.f}; acc[n] = z; }

  const int ar = t >> 2, ac = (t & 3) * 8;
  const int bkr = t >> 3, bnc = (t & 7) * 8;

  for (int kt = 0; kt < 18; ++kt){
    const int k0 = kt * 32;
    *(short8*)&As[ar][ac] = *(const short8*)(AO + (m0 + ar) * 576 + k0 + ac);
    {
      const float* src = Wo + (k0 + bkr) * 576 + nb + bnc;
      float4 v0 = *(const float4*)src;
      float4 v1 = *(const float4*)(src + 4);
      Bs[bnc+0][bkr] = f2bf(v0.x); Bs[bnc+1][bkr] = f2bf(v0.y);
      Bs[bnc+2][bkr] = f2bf(v0.z); Bs[bnc+3][bkr] = f2bf(v0.w);
      Bs[bnc+4][bkr] = f2bf(v1.x); Bs[bnc+5][bkr] = f2bf(v1.y);
      Bs[bnc+6][bkr] = f2bf(v1.z); Bs[bnc+7][bkr] = f2bf(v1.w);
    }
    __syncthreads();
    short8 af = *(const short8*)&As[w*16 + l15][lg*8];
    #pragma unroll
    for (int n = 0; n < 4; ++n){
      short8 bf = *(const short8*)&Bs[n*16 + l15][lg*8];
      acc[n] = __builtin_amdgcn_mfma_f32_16x16x32_bf16(af, bf, acc[n], 0, 0, 0);
    }
    __syncthreads();
  }

  #pragma unroll
  for (int reg = 0; reg < 4; ++reg){
    const int grow = m0 + w*16 + lg*4 + reg;
    float* dst = out + (size_t)grow * 576 + nb;
    #pragma unroll
    for (int n = 0; n < 4; ++n) dst[n*16 + l15] = acc[n][reg];
  }
}

extern "C" void kernel_launch(void* const* d_in, const int* in_sizes, int n_in,
                              void* d_out, int out_size, void* d_ws, size_t ws_size,
                              hipStream_t stream) {
  const float* x  = (const float*)d_in[0];
  // d_in[1] = attention_mask: known-causal, never read.
  const float* Wq = (const float*)d_in[2];
  const float* Wk = (const float*)d_in[3];
  const float* Wv = (const float*)d_in[4];
  const float* Wo = (const float*)d_in[5];
  float* out = (float*)d_out;

  char* ws = (char*)d_ws;
  const size_t XB_BYTES = (size_t)NBATCH*SEQ*HID*2;          // 9,437,184
  const size_t Q_BYTES  = (size_t)NBATCH*NHEADS*SEQ*HD*2;    // 9,437,184
  const size_t K_BYTES  = (size_t)NBATCH*KVHEADS*SEQ*HD*2;   // 3,145,728
  const size_t V_BYTES  = K_BYTES;
  const size_t BASE     = XB_BYTES + Q_BYTES + K_BYTES + V_BYTES;  // 25,165,824

  // choose chunk size: prefer finest split that fits the workspace
  int CS = 128;
  {
    const int cands[3] = {16, 32, 64};
    for (int ci = 0; ci < 3; ++ci){
      const int cs = cands[ci];
      const int T = NQ32 / cs;
      const size_t S = (size_t)NBH * cs * T * (T + 1) / 2;
      const size_t need = BASE + S*(32*64)*2 + 2*S*32*4;
      if (ws_size >= need){ CS = cs; break; }
    }
  }
  const int T  = NQ32 / CS;
  const size_t S = (size_t)NBH * CS * T * (T + 1) / 2;   // total chunk slots
  const size_t PO_BYTES = S * (32*64) * 2;
  const size_t PM_BYTES = S * 32 * 4;

  unsigned short* xb = (unsigned short*)ws;
  unsigned short* Q  = (unsigned short*)(ws + XB_BYTES);
  unsigned short* K  = (unsigned short*)(ws + XB_BYTES + Q_BYTES);
  unsigned short* Vt = (unsigned short*)(ws + XB_BYTES + Q_BYTES + K_BYTES);
  unsigned short* PO = (unsigned short*)(ws + BASE);
  float* Pm = (float*)(ws + BASE + PO_BYTES);
  float* Pl = (float*)(ws + BASE + PO_BYTES + PM_BYTES);
  unsigned short* AO = xb;  // reuse: xb dead after k_qkv

  hipLaunchKernelGGL(k_cast, dim3((NBATCH*SEQ*HID)/1024), dim3(256), 0, stream,
                     x, xb, NBATCH*SEQ*HID);
  hipLaunchKernelGGL(k_qkv, dim3(15, (NBATCH*SEQ)/64), dim3(256), 0, stream,
                     xb, Wq, Wk, Wv, Q, K, Vt);
  hipLaunchKernelGGL(k_attn6, dim3((unsigned)S), dim3(64), 0, stream,
                     Q, K, Vt, AO, PO, Pm, Pl, CS, T);
  if (NQ32 > CS)
    hipLaunchKernelGGL(k_comb, dim3(NBH*(NQ32 - CS)), dim3(64), 0, stream,
                       PO, Pm, Pl, AO, CS, T);
  hipLaunchKernelGGL(k_oproj, dim3(9, (NBATCH*SEQ)/64), dim3(256), 0, stream,
                     AO, Wo, out);
}

// Round 8
// 224.035 us; speedup vs baseline: 1.6632x; 1.6632x over previous
//
#include <hip/hip_runtime.h>
#include <hip/hip_bf16.h>
#include <math.h>

#define HID 576
#define NHEADS 9
#define KVHEADS 3
#define HD 64
#define SEQ 4096
#define NBATCH 2

typedef __attribute__((ext_vector_type(8))) short short8;
typedef __attribute__((ext_vector_type(4))) float f32x4;
typedef __attribute__((ext_vector_type(16))) float f32x16;
typedef __attribute__((ext_vector_type(4))) unsigned int u32x4;

#define EXP2F(x) exp2f(x)

// 0.125 (1/sqrt(64)) * log2(e): folded into Q so softmax runs in exp2 domain
#define QSCALE 0.18033688011112042f

#define NBH (NBATCH*NHEADS)            // 18
#define NPAIR 64                       // 64-row pairs per (b,h)
#define JSPLIT 32                      // pairs with j >= JSPLIT are split in 2
#define NHEAVYP ((NPAIR - JSPLIT) * NBH)   // 576 heavy pairs -> 1152 waves
#define NLIGHTP (JSPLIT * NBH)             // 576 light pairs
#define NWAVESP (NHEAVYP*2 + NLIGHTP)      // 1728

__device__ __forceinline__ unsigned short f2bf(float f){
  unsigned int u = __float_as_uint(f);
  u += 0x7FFFu + ((u >> 16) & 1u);
  return (unsigned short)(u >> 16);
}
__device__ __forceinline__ float bf2f(unsigned short u){
  return __uint_as_float(((unsigned)u) << 16);
}

__device__ __forceinline__ unsigned cvt_pk_bf16(float lo, float hi){
  unsigned r;
  asm("v_cvt_pk_bf16_f32 %0, %1, %2" : "=v"(r) : "v"(lo), "v"(hi));
  return r;
}

// ---------------- cast x (fp32) -> bf16 ----------------
__global__ __launch_bounds__(256) void k_cast(const float* __restrict__ x,
                                              unsigned short* __restrict__ xb, int n){
  int i = (blockIdx.x * 256 + threadIdx.x) * 4;
  if (i < n){
    float4 v = *(const float4*)(x + i);
    ushort4 o;
    o.x = f2bf(v.x); o.y = f2bf(v.y); o.z = f2bf(v.z); o.w = f2bf(v.w);
    *(ushort4*)(xb + i) = o;
  }
}

// ---------------- fused QKV GEMM + RoPE (Q pre-scaled by 0.125*log2e) ----------------
__global__ __launch_bounds__(256) void k_qkv(const unsigned short* __restrict__ xb,
    const float* __restrict__ Wq, const float* __restrict__ Wk, const float* __restrict__ Wv,
    unsigned short* __restrict__ Qo, unsigned short* __restrict__ Ko,
    unsigned short* __restrict__ Vt)
{
  __shared__ unsigned short As[64][40];
  __shared__ unsigned short Bs[64][40];
  const int tn = blockIdx.x;
  const int m0 = blockIdx.y * 64;
  const int t  = threadIdx.x;
  const int w  = t >> 6;
  const int l  = t & 63;
  const int l15 = l & 15, lg = l >> 4;

  const float* W; int nb, ldw;
  if (tn < 9)      { W = Wq; nb = tn * 64;        ldw = 576; }
  else if (tn < 12){ W = Wk; nb = (tn - 9) * 64;  ldw = 192; }
  else             { W = Wv; nb = (tn - 12) * 64; ldw = 192; }

  f32x4 acc[4];
  #pragma unroll
  for (int n = 0; n < 4; ++n){ f32x4 z = {0.f,0.f,0.f,0.f}; acc[n] = z; }

  const int ar = t >> 2, ac = (t & 3) * 8;
  const int bkr = t >> 3, bnc = (t & 7) * 8;

  for (int kt = 0; kt < 18; ++kt){
    const int k0 = kt * 32;
    *(short8*)&As[ar][ac] = *(const short8*)(xb + (m0 + ar) * 576 + k0 + ac);
    {
      const float* src = W + (k0 + bkr) * ldw + nb + bnc;
      float4 v0 = *(const float4*)src;
      float4 v1 = *(const float4*)(src + 4);
      Bs[bnc+0][bkr] = f2bf(v0.x); Bs[bnc+1][bkr] = f2bf(v0.y);
      Bs[bnc+2][bkr] = f2bf(v0.z); Bs[bnc+3][bkr] = f2bf(v0.w);
      Bs[bnc+4][bkr] = f2bf(v1.x); Bs[bnc+5][bkr] = f2bf(v1.y);
      Bs[bnc+6][bkr] = f2bf(v1.z); Bs[bnc+7][bkr] = f2bf(v1.w);
    }
    __syncthreads();
    short8 af = *(const short8*)&As[w*16 + l15][lg*8];
    #pragma unroll
    for (int n = 0; n < 4; ++n){
      short8 bf = *(const short8*)&Bs[n*16 + l15][lg*8];
      acc[n] = __builtin_amdgcn_mfma_f32_16x16x32_bf16(af, bf, acc[n], 0, 0, 0);
    }
    __syncthreads();
  }

  // RoPE: pairs (d, d+32) = frags (n, n+2), same lane, same reg.
  if (tn < 12){
    #pragma unroll
    for (int np = 0; np < 2; ++np){
      const int p = np*16 + l15;
      const float freq = exp2f((float)p * -0.41524101186f);  // 10000^(-p/32)
      #pragma unroll
      for (int reg = 0; reg < 4; ++reg){
        const int grow = m0 + w*16 + lg*4 + reg;
        const int s = grow & (SEQ-1);
        float si, co;
        sincosf((float)s * freq, &si, &co);
        float v0 = acc[np][reg], v1 = acc[np+2][reg];
        acc[np][reg]   = v0*co - v1*si;
        acc[np+2][reg] = v1*co + v0*si;
      }
    }
  }

  if (tn < 9){
    const int h = tn;
    #pragma unroll
    for (int reg = 0; reg < 4; ++reg){
      const int grow = m0 + w*16 + lg*4 + reg;
      const int b = grow >> 12, s = grow & (SEQ-1);
      unsigned short* dst = Qo + ((b*NHEADS + h)*SEQ + s)*64;
      #pragma unroll
      for (int n = 0; n < 4; ++n) dst[n*16 + l15] = f2bf(acc[n][reg] * QSCALE);
    }
  } else if (tn < 12){
    const int h = tn - 9;
    #pragma unroll
    for (int reg = 0; reg < 4; ++reg){
      const int grow = m0 + w*16 + lg*4 + reg;
      const int b = grow >> 12, s = grow & (SEQ-1);
      unsigned short* dst = Ko + ((b*KVHEADS + h)*SEQ + s)*64;
      #pragma unroll
      for (int n = 0; n < 4; ++n) dst[n*16 + l15] = f2bf(acc[n][reg]);
    }
  } else {
    const int h = tn - 12;
    #pragma unroll
    for (int reg = 0; reg < 4; ++reg){
      const int grow = m0 + w*16 + lg*4 + reg;
      const int b = grow >> 12, s = grow & (SEQ-1);
      #pragma unroll
      for (int n = 0; n < 4; ++n)
        Vt[((b*KVHEADS + h)*64 + n*16 + l15)*SEQ + s] = f2bf(acc[n][reg]);
    }
  }
}

// ---------------- causal flash attention: 1 wave / PAIR of 32-row q-blocks ----------------
// Both q-blocks share the same K/V fragment loads (2x ILP, same traffic).
// Heavy pairs (j >= JSPLIT) split their key range in 2; bf16 partials merged by k_comb.
__global__ __launch_bounds__(64, 2) void k_attn8(const unsigned short* __restrict__ Q,
    const unsigned short* __restrict__ K, const unsigned short* __restrict__ Vt,
    unsigned short* __restrict__ AO,
    unsigned short* __restrict__ PO, float* __restrict__ Pm, float* __restrict__ Pl,
    int do_split)
{
  const int bid = blockIdx.x;
  int j, bh, s0, s1;
  bool partial;
  if (do_split && bid < NHEAVYP*2){
    const int hr = bid >> 1, hf = bid & 1;
    j  = (NPAIR-1) - hr / NBH;          // 63 down to 32
    bh = hr % NBH;
    const int ntot = 2*j + 2, sh = j + 1;
    s0 = hf ? sh : 0;  s1 = hf ? ntot : sh;
    partial = true;
  } else {
    const int b2  = do_split ? bid - NHEAVYP*2 : bid;
    const int jmx = do_split ? JSPLIT : NPAIR;
    j  = (jmx-1) - b2 / NBH;
    bh = b2 % NBH;
    s0 = 0; s1 = 2*j + 2;
    partial = false;
  }

  const int b  = bh / NHEADS, h = bh % NHEADS, kvh = h / 3;
  const int l  = threadIdx.x;
  const int q31 = l & 31, half = l >> 5;
  const int qA0 = j*64, qB0 = j*64 + 32;
  const int myqA = qA0 + q31, myqB = qB0 + q31;

  // Q fragments for both blocks (lane holds q-row qX0+q31, d = di*16 + half*8 + jj)
  const unsigned short* QpA = Q + ((size_t)(b*NHEADS + h)*SEQ + qA0 + q31)*HD + half*8;
  const short8 qa0 = *(const short8*)(QpA);
  const short8 qa1 = *(const short8*)(QpA + 16);
  const short8 qa2 = *(const short8*)(QpA + 32);
  const short8 qa3 = *(const short8*)(QpA + 48);
  const unsigned short* QpB = QpA + (size_t)32*HD;
  const short8 qb0 = *(const short8*)(QpB);
  const short8 qb1 = *(const short8*)(QpB + 16);
  const short8 qb2 = *(const short8*)(QpB + 32);
  const short8 qb3 = *(const short8*)(QpB + 48);

  const unsigned short* Kp  = K  + (size_t)(b*KVHEADS + kvh)*SEQ*HD + (size_t)q31*HD + half*8;
  const unsigned short* Vp0 = Vt + (size_t)(b*KVHEADS + kvh)*HD*SEQ + (size_t)q31*SEQ + half*8;
  const unsigned short* Vp1 = Vp0 + (size_t)32*SEQ;

  f32x16 aA0 = {}, aA1 = {}, aB0 = {}, aB1 = {};
  float mA = -3e38f, lsA = 0.f, mB = -3e38f, lsB = 0.f;

  // prefetch K fragments for first subtile
  const unsigned short* kp0 = Kp + (size_t)(s0*32)*HD;
  short8 ckf0 = *(const short8*)(kp0);
  short8 ckf1 = *(const short8*)(kp0 + 16);
  short8 ckf2 = *(const short8*)(kp0 + 32);
  short8 ckf3 = *(const short8*)(kp0 + 48);

  for (int s = s0; s < s1; ++s){
    const int ks = s*32;

    // V loads for current subtile (shared by both blocks, consumed at the end)
    short8 vf00 = *(const short8*)(Vp0 + ks);
    short8 vf01 = *(const short8*)(Vp0 + ks + 16);
    short8 vf10 = *(const short8*)(Vp1 + ks);
    short8 vf11 = *(const short8*)(Vp1 + ks + 16);

    // ---- QK^T for both blocks on shared K fragments
    __builtin_amdgcn_s_setprio(1);
    f32x16 stA = {}, stB = {};
    stA = __builtin_amdgcn_mfma_f32_32x32x16_bf16(ckf0, qa0, stA, 0,0,0);
    stB = __builtin_amdgcn_mfma_f32_32x32x16_bf16(ckf0, qb0, stB, 0,0,0);
    stA = __builtin_amdgcn_mfma_f32_32x32x16_bf16(ckf1, qa1, stA, 0,0,0);
    stB = __builtin_amdgcn_mfma_f32_32x32x16_bf16(ckf1, qb1, stB, 0,0,0);
    stA = __builtin_amdgcn_mfma_f32_32x32x16_bf16(ckf2, qa2, stA, 0,0,0);
    stB = __builtin_amdgcn_mfma_f32_32x32x16_bf16(ckf2, qb2, stB, 0,0,0);
    stA = __builtin_amdgcn_mfma_f32_32x32x16_bf16(ckf3, qa3, stA, 0,0,0);
    stB = __builtin_amdgcn_mfma_f32_32x32x16_bf16(ckf3, qb3, stB, 0,0,0);
    __builtin_amdgcn_s_setprio(0);

    // prefetch next subtile's K fragments
    short8 nkf0, nkf1, nkf2, nkf3;
    const bool more = (s + 1 < s1);
    if (more){
      const unsigned short* kp = Kp + (size_t)(ks + 32)*HD;
      nkf0 = *(const short8*)(kp);
      nkf1 = *(const short8*)(kp + 16);
      nkf2 = *(const short8*)(kp + 32);
      nkf3 = *(const short8*)(kp + 48);
    }

    // causal masks: A needs masking for s >= 2j (diag at 2j, full at 2j+1 -> P=0);
    // B only at its diagonal s == 2j+1
    if (s >= 2*j){
      #pragma unroll
      for (int r = 0; r < 16; ++r){
        const int k = ks + (r & 3) + 8*(r >> 2) + 4*half;
        if (k > myqA) stA[r] = -3e38f;
      }
    }
    if (s == 2*j + 1){
      #pragma unroll
      for (int r = 0; r < 16; ++r){
        const int k = ks + (r & 3) + 8*(r >> 2) + 4*half;
        if (k > myqB) stB[r] = -3e38f;
      }
    }

    // ---- softmax A
    {
      float a0 = fmaxf(stA[0], stA[1]),  a1 = fmaxf(stA[2], stA[3]);
      float a2 = fmaxf(stA[4], stA[5]),  a3 = fmaxf(stA[6], stA[7]);
      float a4 = fmaxf(stA[8], stA[9]),  a5 = fmaxf(stA[10], stA[11]);
      float a6 = fmaxf(stA[12], stA[13]),a7 = fmaxf(stA[14], stA[15]);
      float b0 = fmaxf(a0, a1), b1 = fmaxf(a2, a3), b2 = fmaxf(a4, a5), b3 = fmaxf(a6, a7);
      float pmax = fmaxf(fmaxf(b0, b1), fmaxf(b2, b3));
      pmax = fmaxf(pmax, __shfl_xor(pmax, 32));
      if (__any(pmax > mA + 8.0f)){
        const float mnew  = fmaxf(mA, pmax);
        const float alpha = EXP2F(mA - mnew);
        mA = mnew;
        lsA *= alpha;
        #pragma unroll
        for (int r = 0; r < 16; ++r){
          const float ar = __shfl(alpha, (r & 3) + 8*(r >> 2) + 4*half);
          aA0[r] *= ar; aA1[r] *= ar;
        }
      }
      float psum = 0.f;
      #pragma unroll
      for (int r = 0; r < 16; ++r){ stA[r] = EXP2F(stA[r] - mA); psum += stA[r]; }
      psum += __shfl_xor(psum, 32);
      lsA += psum;
    }
    // ---- softmax B
    {
      float a0 = fmaxf(stB[0], stB[1]),  a1 = fmaxf(stB[2], stB[3]);
      float a2 = fmaxf(stB[4], stB[5]),  a3 = fmaxf(stB[6], stB[7]);
      float a4 = fmaxf(stB[8], stB[9]),  a5 = fmaxf(stB[10], stB[11]);
      float a6 = fmaxf(stB[12], stB[13]),a7 = fmaxf(stB[14], stB[15]);
      float b0 = fmaxf(a0, a1), b1 = fmaxf(a2, a3), b2 = fmaxf(a4, a5), b3 = fmaxf(a6, a7);
      float pmax = fmaxf(fmaxf(b0, b1), fmaxf(b2, b3));
      pmax = fmaxf(pmax, __shfl_xor(pmax, 32));
      if (__any(pmax > mB + 8.0f)){
        const float mnew  = fmaxf(mB, pmax);
        const float alpha = EXP2F(mB - mnew);
        mB = mnew;
        lsB *= alpha;
        #pragma unroll
        for (int r = 0; r < 16; ++r){
          const float ar = __shfl(alpha, (r & 3) + 8*(r >> 2) + 4*half);
          aB0[r] *= ar; aB1[r] *= ar;
        }
      }
      float psum = 0.f;
      #pragma unroll
      for (int r = 0; r < 16; ++r){ stB[r] = EXP2F(stB[r] - mB); psum += stB[r]; }
      psum += __shfl_xor(psum, 32);
      lsB += psum;
    }

    // ---- pack both P tiles -> PV A-frags (v_permlane32_swap, T12)
    union { u32x4 u; short8 s; } paA0, paA1, paB0, paB1;
    {
      unsigned cA = cvt_pk_bf16(stA[0], stA[1]);
      unsigned cB = cvt_pk_bf16(stA[2], stA[3]);
      unsigned cC = cvt_pk_bf16(stA[4], stA[5]);
      unsigned cD = cvt_pk_bf16(stA[6], stA[7]);
      asm("v_permlane32_swap_b32 %0, %1" : "+v"(cA), "+v"(cC));
      asm("v_permlane32_swap_b32 %0, %1" : "+v"(cB), "+v"(cD));
      paA0.u[0] = cA; paA0.u[1] = cB; paA0.u[2] = cC; paA0.u[3] = cD;
      unsigned eA = cvt_pk_bf16(stA[8],  stA[9]);
      unsigned eB = cvt_pk_bf16(stA[10], stA[11]);
      unsigned eC = cvt_pk_bf16(stA[12], stA[13]);
      unsigned eD = cvt_pk_bf16(stA[14], stA[15]);
      asm("v_permlane32_swap_b32 %0, %1" : "+v"(eA), "+v"(eC));
      asm("v_permlane32_swap_b32 %0, %1" : "+v"(eB), "+v"(eD));
      paA1.u[0] = eA; paA1.u[1] = eB; paA1.u[2] = eC; paA1.u[3] = eD;
    }
    {
      unsigned cA = cvt_pk_bf16(stB[0], stB[1]);
      unsigned cB = cvt_pk_bf16(stB[2], stB[3]);
      unsigned cC = cvt_pk_bf16(stB[4], stB[5]);
      unsigned cD = cvt_pk_bf16(stB[6], stB[7]);
      asm("v_permlane32_swap_b32 %0, %1" : "+v"(cA), "+v"(cC));
      asm("v_permlane32_swap_b32 %0, %1" : "+v"(cB), "+v"(cD));
      paB0.u[0] = cA; paB0.u[1] = cB; paB0.u[2] = cC; paB0.u[3] = cD;
      unsigned eA = cvt_pk_bf16(stB[8],  stB[9]);
      unsigned eB = cvt_pk_bf16(stB[10], stB[11]);
      unsigned eC = cvt_pk_bf16(stB[12], stB[13]);
      unsigned eD = cvt_pk_bf16(stB[14], stB[15]);
      asm("v_permlane32_swap_b32 %0, %1" : "+v"(eA), "+v"(eC));
      asm("v_permlane32_swap_b32 %0, %1" : "+v"(eB), "+v"(eD));
      paB1.u[0] = eA; paB1.u[1] = eB; paB1.u[2] = eC; paB1.u[3] = eD;
    }

    // ---- PV for both blocks on shared V fragments
    __builtin_amdgcn_s_setprio(1);
    aA0 = __builtin_amdgcn_mfma_f32_32x32x16_bf16(paA0.s, vf00, aA0, 0,0,0);
    aB0 = __builtin_amdgcn_mfma_f32_32x32x16_bf16(paB0.s, vf00, aB0, 0,0,0);
    aA0 = __builtin_amdgcn_mfma_f32_32x32x16_bf16(paA1.s, vf01, aA0, 0,0,0);
    aB0 = __builtin_amdgcn_mfma_f32_32x32x16_bf16(paB1.s, vf01, aB0, 0,0,0);
    aA1 = __builtin_amdgcn_mfma_f32_32x32x16_bf16(paA0.s, vf10, aA1, 0,0,0);
    aB1 = __builtin_amdgcn_mfma_f32_32x32x16_bf16(paB0.s, vf10, aB1, 0,0,0);
    aA1 = __builtin_amdgcn_mfma_f32_32x32x16_bf16(paA1.s, vf11, aA1, 0,0,0);
    aB1 = __builtin_amdgcn_mfma_f32_32x32x16_bf16(paB1.s, vf11, aB1, 0,0,0);
    __builtin_amdgcn_s_setprio(0);

    if (more){ ckf0 = nkf0; ckf1 = nkf1; ckf2 = nkf2; ckf3 = nkf3; }
  }

  if (partial){
    // slots: A at bid*2, B at bid*2+1 (bf16 unnormalized O + fp32 m,l)
    unsigned short* PA = PO + (size_t)(bid*2)   * (32*64);
    unsigned short* PB = PO + (size_t)(bid*2+1) * (32*64);
    #pragma unroll
    for (int r = 0; r < 16; ++r){
      const int rq = (r & 3) + 8*(r >> 2) + 4*half;
      PA[rq*64 + q31]      = f2bf(aA0[r]);
      PA[rq*64 + q31 + 32] = f2bf(aA1[r]);
      PB[rq*64 + q31]      = f2bf(aB0[r]);
      PB[rq*64 + q31 + 32] = f2bf(aB1[r]);
    }
    if (half == 0){
      Pm[(size_t)(bid*2)*32 + q31]   = mA;
      Pl[(size_t)(bid*2)*32 + q31]   = lsA;
      Pm[(size_t)(bid*2+1)*32 + q31] = mB;
      Pl[(size_t)(bid*2+1)*32 + q31] = lsB;
    }
  } else {
    const float liA = 1.0f / lsA, liB = 1.0f / lsB;
    #pragma unroll
    for (int r = 0; r < 16; ++r){
      const int rq = (r & 3) + 8*(r >> 2) + 4*half;
      const float la = __shfl(liA, rq), lb = __shfl(liB, rq);
      const size_t baseA = ((size_t)(b*SEQ + qA0 + rq))*576 + h*64 + q31;
      AO[baseA]      = f2bf(aA0[r] * la);
      AO[baseA + 32] = f2bf(aA1[r] * la);
      const size_t baseB = ((size_t)(b*SEQ + qB0 + rq))*576 + h*64 + q31;
      AO[baseB]      = f2bf(aB0[r] * lb);
      AO[baseB + 32] = f2bf(aB1[r] * lb);
    }
  }
}

// ---------------- merge pair split-K partials (2 chunks per q-block) ----------------
__global__ __launch_bounds__(64) void k_comb(const unsigned short* __restrict__ PO,
    const float* __restrict__ Pm, const float* __restrict__ Pl,
    unsigned short* __restrict__ AO)
{
  const int bid = blockIdx.x;              // 0..NHEAVYP*2-1: (pair, block X)
  const int hr = bid >> 1, X = bid & 1;
  const int j  = (NPAIR-1) - hr / NBH;
  const int bh = hr % NBH;
  const int b = bh / NHEADS, h = bh % NHEADS;
  const int q0 = j*64 + 32*X;
  const int d = threadIdx.x;               // 0..63

  const int s0id = (hr*2 + 0)*2 + X;       // chunk 0's slot for block X
  const int s1id = (hr*2 + 1)*2 + X;       // chunk 1's slot
  const unsigned short* O0 = PO + (size_t)s0id * (32*64);
  const unsigned short* O1 = PO + (size_t)s1id * (32*64);

  for (int row = 0; row < 32; ++row){
    const float m0 = Pm[(size_t)s0id*32 + row], m1 = Pm[(size_t)s1id*32 + row];
    const float M  = fmaxf(m0, m1);
    const float w0 = exp2f(m0 - M), w1 = exp2f(m1 - M);
    const float linv = 1.0f / (Pl[(size_t)s0id*32 + row]*w0 + Pl[(size_t)s1id*32 + row]*w1);
    const float o = (bf2f(O0[row*64 + d])*w0 + bf2f(O1[row*64 + d])*w1) * linv;
    AO[((size_t)(b*SEQ + q0 + row))*576 + h*64 + d] = f2bf(o);
  }
}

// ---------------- output projection: AO(bf16) @ Wo -> out(fp32) ----------------
__global__ __launch_bounds__(256) void k_oproj(const unsigned short* __restrict__ AO,
    const float* __restrict__ Wo, float* __restrict__ out)
{
  __shared__ unsigned short As[64][40];
  __shared__ unsigned short Bs[64][40];
  const int tn = blockIdx.x;
  const int m0 = blockIdx.y * 64;
  const int t  = threadIdx.x;
  const int w  = t >> 6;
  const int l  = t & 63;
  const int l15 = l & 15, lg = l >> 4;
  const int nb = tn * 64;

  f32x4 acc[4];
  #pragma unroll
  for (int n = 0; n < 4; ++n){ f32x4 z = {0.f,0.f,0.f,0.f}; acc[n] = z; }

  const int ar = t >> 2, ac = (t & 3) * 8;
  const int bkr = t >> 3, bnc = (t & 7) * 8;

  for (int kt = 0; kt < 18; ++kt){
    const int k0 = kt * 32;
    *(short8*)&As[ar][ac] = *(const short8*)(AO + (m0 + ar) * 576 + k0 + ac);
    {
      const float* src = Wo + (k0 + bkr) * 576 + nb + bnc;
      float4 v0 = *(const float4*)src;
      float4 v1 = *(const float4*)(src + 4);
      Bs[bnc+0][bkr] = f2bf(v0.x); Bs[bnc+1][bkr] = f2bf(v0.y);
      Bs[bnc+2][bkr] = f2bf(v0.z); Bs[bnc+3][bkr] = f2bf(v0.w);
      Bs[bnc+4][bkr] = f2bf(v1.x); Bs[bnc+5][bkr] = f2bf(v1.y);
      Bs[bnc+6][bkr] = f2bf(v1.z); Bs[bnc+7][bkr] = f2bf(v1.w);
    }
    __syncthreads();
    short8 af = *(const short8*)&As[w*16 + l15][lg*8];
    #pragma unroll
    for (int n = 0; n < 4; ++n){
      short8 bf = *(const short8*)&Bs[n*16 + l15][lg*8];
      acc[n] = __builtin_amdgcn_mfma_f32_16x16x32_bf16(af, bf, acc[n], 0, 0, 0);
    }
    __syncthreads();
  }

  #pragma unroll
  for (int reg = 0; reg < 4; ++reg){
    const int grow = m0 + w*16 + lg*4 + reg;
    float* dst = out + (size_t)grow * 576 + nb;
    #pragma unroll
    for (int n = 0; n < 4; ++n) dst[n*16 + l15] = acc[n][reg];
  }
}

extern "C" void kernel_launch(void* const* d_in, const int* in_sizes, int n_in,
                              void* d_out, int out_size, void* d_ws, size_t ws_size,
                              hipStream_t stream) {
  const float* x  = (const float*)d_in[0];
  // d_in[1] = attention_mask: known-causal, never read.
  const float* Wq = (const float*)d_in[2];
  const float* Wk = (const float*)d_in[3];
  const float* Wv = (const float*)d_in[4];
  const float* Wo = (const float*)d_in[5];
  float* out = (float*)d_out;

  char* ws = (char*)d_ws;
  const size_t XB_BYTES = (size_t)NBATCH*SEQ*HID*2;          // 9,437,184
  const size_t Q_BYTES  = (size_t)NBATCH*NHEADS*SEQ*HD*2;    // 9,437,184
  const size_t K_BYTES  = (size_t)NBATCH*KVHEADS*SEQ*HD*2;   // 3,145,728
  const size_t V_BYTES  = K_BYTES;
  const size_t BASE     = XB_BYTES + Q_BYTES + K_BYTES + V_BYTES;  // 25,165,824
  const size_t NSLOT    = (size_t)NHEAVYP*2*2;                     // 2304 slots
  const size_t PO_BYTES = NSLOT * (32*64) * 2;                     // 9,437,184 (bf16)
  const size_t PM_BYTES = NSLOT * 32 * 4;                          // 294,912

  unsigned short* xb = (unsigned short*)ws;
  unsigned short* Q  = (unsigned short*)(ws + XB_BYTES);
  unsigned short* K  = (unsigned short*)(ws + XB_BYTES + Q_BYTES);
  unsigned short* Vt = (unsigned short*)(ws + XB_BYTES + Q_BYTES + K_BYTES);
  unsigned short* PO = (unsigned short*)(ws + BASE);
  float* Pm = (float*)(ws + BASE + PO_BYTES);
  float* Pl = (float*)(ws + BASE + PO_BYTES + PM_BYTES);
  unsigned short* AO = xb;  // reuse: xb dead after k_qkv

  const int do_split = (ws_size >= BASE + PO_BYTES + 2*PM_BYTES) ? 1 : 0;

  hipLaunchKernelGGL(k_cast, dim3((NBATCH*SEQ*HID)/1024), dim3(256), 0, stream,
                     x, xb, NBATCH*SEQ*HID);
  hipLaunchKernelGGL(k_qkv, dim3(15, (NBATCH*SEQ)/64), dim3(256), 0, stream,
                     xb, Wq, Wk, Wv, Q, K, Vt);
  hipLaunchKernelGGL(k_attn8, dim3(do_split ? NWAVESP : NBH*NPAIR), dim3(64), 0, stream,
                     Q, K, Vt, AO, PO, Pm, Pl, do_split);
  if (do_split)
    hipLaunchKernelGGL(k_comb, dim3(NHEAVYP*2), dim3(64), 0, stream, PO, Pm, Pl, AO);
  hipLaunchKernelGGL(k_oproj, dim3(9, (NBATCH*SEQ)/64), dim3(256), 0, stream,
                     AO, Wo, out);
}